// Round 8
// baseline (520.779 us; speedup 1.0000x reference)
//
#include <hip/hip_runtime.h>
#include <hip/hip_bf16.h>

// ConvSelfAttn: B=8, N=4096, C=64, d=8. FP32 I/O.
// R8 = R7 with cvt_pkrtz type fix. attn: 512-thr blocks, key-split 8, grid
// 1024 -> 4 blocks/CU x 8 waves = 32 waves/CU. launch_bounds(512,8) pins
// VGPR<=64. LDS union: Obuf overlays Pbuf post-loop. Proj: Vs stride 68.

#define BB 8
#define NN 4096
#define CC 64
#define PSTRIDE 72
#define LOG2E 1.44269504088896f

typedef _Float16 f16;
typedef _Float16 half8 __attribute__((ext_vector_type(8)));
typedef _Float16 half4 __attribute__((ext_vector_type(4)));
typedef __fp16 fp16x2 __attribute__((ext_vector_type(2)));
typedef float floatx4 __attribute__((ext_vector_type(4)));

static __device__ inline half4 pack4(float a, float b, float c, float d) {
    fp16x2 lo = __builtin_amdgcn_cvt_pkrtz(a, b);
    fp16x2 hi = __builtin_amdgcn_cvt_pkrtz(c, d);
    unsigned int lou = __builtin_bit_cast(unsigned int, lo);
    unsigned int hiu = __builtin_bit_cast(unsigned int, hi);
    unsigned long long packed = (unsigned long long)lou | ((unsigned long long)hiu << 32);
    return __builtin_bit_cast(half4, packed);
}

// ws layouts (halfs):
//   Qh    [B*N][8]                       row-major, Q pre-scaled by log2e
//   Kfrag [B][256 kblk][32 lane][4]      A-frag for 16x16x16 (quads 0-1)
//   Vfrag [B][128 kb32][4 ct][64 lane][8] A-frag for 16x16x32 PV

// ---------------- fused projection + fragment repack ----------------
__global__ __launch_bounds__(256) void proj_all_kernel(
    const float* __restrict__ x,
    const float* __restrict__ wq, const float* __restrict__ bq,
    const float* __restrict__ wk, const float* __restrict__ bk,
    const float* __restrict__ wv, const float* __restrict__ bv,
    f16* __restrict__ Qh, f16* __restrict__ Kf, f16* __restrict__ Vf)
{
    __shared__ alignas(16) f16 Ws[80][PSTRIDE];  // rows 0-63=V, 64-71=Q, 72-79=K
    __shared__ float Bs[80];
    __shared__ alignas(16) f16 Vs[64][68];       // [pixel][ch], pitch 68
    __shared__ alignas(16) f16 Ks[64][12];       // [pixel][ch]
    const int tid = threadIdx.x;

    for (int i = tid; i < 4096; i += 256) {
        int cin = i >> 6, cout = i & 63;
        Ws[cout][cin] = (f16)wv[i];
    }
    for (int i = tid; i < 512; i += 256) {
        int cin = i >> 3, c = i & 7;
        Ws[64 + c][cin] = (f16)(wq[i] * LOG2E);
        Ws[72 + c][cin] = (f16)wk[i];
    }
    if (tid < 80)
        Bs[tid] = (tid < 64) ? bv[tid]
                : (tid < 72 ? bq[tid - 64] * LOG2E : bk[tid - 72]);
    __syncthreads();

    const int wave = tid >> 6, lane = tid & 63;
    const int quad = lane >> 4, n16 = lane & 15;
    const long pb = (long)blockIdx.x * 64;
    const long p0 = pb + wave * 16;
    const int  b   = (int)(pb >> 12);
    const int  nnb = (int)(pb & 4095);

    half8 ax[2];
#pragma unroll
    for (int kh = 0; kh < 2; ++kh) {
        const float* xp = x + (p0 + n16) * 64 + kh * 32 + quad * 8;
        float4 x1 = *(const float4*)xp;
        float4 x2 = *(const float4*)(xp + 4);
        ax[kh][0] = (f16)x1.x; ax[kh][1] = (f16)x1.y;
        ax[kh][2] = (f16)x1.z; ax[kh][3] = (f16)x1.w;
        ax[kh][4] = (f16)x2.x; ax[kh][5] = (f16)x2.y;
        ax[kh][6] = (f16)x2.z; ax[kh][7] = (f16)x2.w;
    }

#pragma unroll
    for (int ct = 0; ct < 5; ++ct) {
        const int cout = (ct < 4) ? ct * 16 + n16 : 64 + n16;
        const float bias = Bs[cout];
        half8 b0 = *(const half8*)(&Ws[cout][quad * 8]);
        half8 b1 = *(const half8*)(&Ws[cout][32 + quad * 8]);
        floatx4 acc = {bias, bias, bias, bias};
        acc = __builtin_amdgcn_mfma_f32_16x16x32_f16(ax[0], b0, acc, 0, 0, 0);
        acc = __builtin_amdgcn_mfma_f32_16x16x32_f16(ax[1], b1, acc, 0, 0, 0);
        if (ct < 4) {
#pragma unroll
            for (int r = 0; r < 4; ++r)
                Vs[wave * 16 + quad * 4 + r][ct * 16 + n16] = (f16)acc[r];
        } else if (n16 < 8) {
            f16* dst = Qh + (p0 + quad * 4) * 8 + n16;
#pragma unroll
            for (int r = 0; r < 4; ++r) dst[r * 8] = (f16)acc[r];
        } else {
#pragma unroll
            for (int r = 0; r < 4; ++r)
                Ks[wave * 16 + quad * 4 + r][n16 - 8] = (f16)acc[r];
        }
    }
    __syncthreads();

#pragma unroll
    for (int u = 0; u < 2; ++u) {
        const int tt = wave * 2 + u;
        const int kb = tt >> 2, ct = tt & 3;
        half8 v;
#pragma unroll
        for (int j = 0; j < 8; ++j)
            v[j] = Vs[kb * 32 + quad * 8 + j][ct * 16 + n16];
        const size_t kbg = (size_t)b * 128 + (nnb >> 5) + kb;
        *(half8*)(Vf + (kbg * 4 + ct) * 512 + lane * 8) = v;
    }
    if (quad < 2) {
        half4 kv;
#pragma unroll
        for (int j = 0; j < 4; ++j)
            kv[j] = Ks[wave * 16 + n16][quad * 4 + j];
        const size_t kbg = (size_t)b * 256 + (nnb >> 4) + wave;
        *(half4*)(Kf + kbg * 128 + lane * 4) = kv;
    }
}

// ---------------- flash attention, S^T form, 32 q/wave, key-split 8 ----------------
// grid B*128 = 1024 x 512 thr; wave = ks (0..7): keys [ks*512,+512), 8 iters.
__global__ __launch_bounds__(512, 8) void attn_kernel(
    const f16* __restrict__ Qh, const f16* __restrict__ Kf,
    const f16* __restrict__ Vf,
    const float* __restrict__ x, const float* __restrict__ gptr,
    float* __restrict__ out)
{
    // union: Pbuf [0,36864) during K-loop; Obuf [0,28672) after barrier.
    __shared__ alignas(16) char smem[8 * 2 * 16 * PSTRIDE * 2 + 2048];
    f16*   Pbuf = (f16*)smem;
    f16*   Obuf = (f16*)smem;                       // 7 x 2 x 64 x 16 halfs
    float* MLs  = (float*)(smem + 8 * 2 * 16 * PSTRIDE * 2);  // 8 x 2 x 16 x 2

    const int tid  = threadIdx.x;
    const int wave = tid >> 6, lane = tid & 63;
    const int quad = lane >> 4, n16 = lane & 15;
    const int ks = wave;                            // 0..7

    const int b  = blockIdx.x & 7;
    const int qt = blockIdx.x >> 3;                 // 0..127
    const size_t bN = (size_t)b * NN;

    half4 bq4[2];
#pragma unroll
    for (int qt2 = 0; qt2 < 2; ++qt2) {
#pragma unroll
        for (int j = 0; j < 4; ++j) bq4[qt2][j] = (f16)0.f;
        if (quad < 2)
            bq4[qt2] = *(const half4*)(Qh + (bN + qt * 32 + qt2 * 16 + n16) * 8 + quad * 4);
    }
    half4 ak[4];
#pragma unroll
    for (int t = 0; t < 4; ++t)
#pragma unroll
        for (int j = 0; j < 4; ++j) ak[t][j] = (f16)0.f;

    floatx4 oacc[2][4];
#pragma unroll
    for (int qt2 = 0; qt2 < 2; ++qt2)
#pragma unroll
        for (int ct = 0; ct < 4; ++ct) oacc[qt2][ct] = (floatx4){0.f, 0.f, 0.f, 0.f};
    float m_run[2] = {-1e30f, -1e30f}, l_loc[2] = {0.f, 0.f};

    const f16* kfb = Kf + ((size_t)b * 256 + ks * 32) * 128;
    const f16* vfb = Vf + ((size_t)b * 128 + ks * 16) * 2048;
    const floatx4 zero4 = {0.f, 0.f, 0.f, 0.f};
    f16* Pw0 = Pbuf + (wave * 2 + 0) * 16 * PSTRIDE;
    f16* Pw1 = Pbuf + (wave * 2 + 1) * 16 * PSTRIDE;

    for (int it = 0; it < 8; ++it) {
        if (quad < 2) {
#pragma unroll
            for (int t = 0; t < 4; ++t)
                ak[t] = *(const half4*)(kfb + (it * 4 + t) * 128 + lane * 4);
        }
        half8 av0[4];
#pragma unroll
        for (int ct = 0; ct < 4; ++ct)
            av0[ct] = *(const half8*)(vfb + ((size_t)(it * 2) * 4 + ct) * 512 + lane * 8);

        floatx4 sf[4];
#pragma unroll
        for (int t = 0; t < 4; ++t)
            sf[t] = __builtin_amdgcn_mfma_f32_16x16x16f16(ak[t], bq4[0], zero4, 0, 0, 0);

        half8 av1[4];
#pragma unroll
        for (int ct = 0; ct < 4; ++ct)
            av1[ct] = *(const half8*)(vfb + ((size_t)(it * 2 + 1) * 4 + ct) * 512 + lane * 8);

#pragma unroll
        for (int qt2 = 0; qt2 < 2; ++qt2) {
            if (qt2 == 1) {
#pragma unroll
                for (int t = 0; t < 4; ++t)
                    sf[t] = __builtin_amdgcn_mfma_f32_16x16x16f16(ak[t], bq4[1], zero4, 0, 0, 0);
            }
            float mx = sf[0][0];
#pragma unroll
            for (int t = 0; t < 4; ++t)
#pragma unroll
                for (int r = 0; r < 4; ++r) mx = fmaxf(mx, sf[t][r]);
            mx = fmaxf(mx, __shfl_xor(mx, 16, 64));
            mx = fmaxf(mx, __shfl_xor(mx, 32, 64));
            const float mnew = fmaxf(m_run[qt2], mx);
            const float alpha = __builtin_exp2f(m_run[qt2] - mnew);
            m_run[qt2] = mnew;
            float rs = 0.f;
#pragma unroll
            for (int t = 0; t < 4; ++t)
#pragma unroll
                for (int r = 0; r < 4; ++r) {
                    float pv = __builtin_exp2f(sf[t][r] - mnew);
                    sf[t][r] = pv;
                    rs += pv;
                }
            l_loc[qt2] = l_loc[qt2] * alpha + rs;
#pragma unroll
            for (int ct = 0; ct < 4; ++ct) oacc[qt2][ct] *= alpha;
            f16* Pw = qt2 ? Pw1 : Pw0;
#pragma unroll
            for (int t = 0; t < 4; ++t) {
                half4 pk = pack4(sf[t][0], sf[t][1], sf[t][2], sf[t][3]);
                *(half4*)(Pw + n16 * PSTRIDE + t * 16 + quad * 4) = pk;
            }
        }
        __asm__ volatile("s_waitcnt lgkmcnt(0)" ::: "memory");

#pragma unroll
        for (int qt2 = 0; qt2 < 2; ++qt2) {
            f16* Pw = qt2 ? Pw1 : Pw0;
            half8 bp0 = *(const half8*)(Pw + n16 * PSTRIDE + quad * 8);
            half8 bp1 = *(const half8*)(Pw + n16 * PSTRIDE + 32 + quad * 8);
#pragma unroll
            for (int ct = 0; ct < 4; ++ct)
                oacc[qt2][ct] = __builtin_amdgcn_mfma_f32_16x16x32_f16(av0[ct], bp0, oacc[qt2][ct], 0, 0, 0);
#pragma unroll
            for (int ct = 0; ct < 4; ++ct)
                oacc[qt2][ct] = __builtin_amdgcn_mfma_f32_16x16x32_f16(av1[ct], bp1, oacc[qt2][ct], 0, 0, 0);
        }
    }

    float l_run[2];
#pragma unroll
    for (int qt2 = 0; qt2 < 2; ++qt2) {
        float l = l_loc[qt2];
        l += __shfl_xor(l, 16, 64);
        l += __shfl_xor(l, 32, 64);
        l_run[qt2] = l;
    }

    __syncthreads();   // all P reads done; Pbuf memory may be reused as Obuf
    if (ks > 0) {
#pragma unroll
        for (int qt2 = 0; qt2 < 2; ++qt2) {
            if (quad == 0) {
                MLs[((ks * 2 + qt2) * 16 + n16) * 2 + 0] = m_run[qt2];
                MLs[((ks * 2 + qt2) * 16 + n16) * 2 + 1] = l_run[qt2];
            }
            half8 p0, p1;
#pragma unroll
            for (int i = 0; i < 4; ++i) {
                p0[i]     = (f16)oacc[qt2][0][i];
                p0[4 + i] = (f16)oacc[qt2][1][i];
                p1[i]     = (f16)oacc[qt2][2][i];
                p1[4 + i] = (f16)oacc[qt2][3][i];
            }
            f16* ob = Obuf + (((ks - 1) * 2 + qt2) * 64 + lane) * 16;
            *(half8*)(ob)     = p0;
            *(half8*)(ob + 8) = p1;
        }
    }
    __syncthreads();
    if (ks == 0) {
        const float g = gptr[0];
#pragma unroll
        for (int qt2 = 0; qt2 < 2; ++qt2) {
            float m = m_run[qt2], l = l_run[qt2];
            float o[16];
#pragma unroll
            for (int ct = 0; ct < 4; ++ct)
#pragma unroll
                for (int r = 0; r < 4; ++r) o[ct * 4 + r] = oacc[qt2][ct][r];
            for (int p = 1; p < 8; ++p) {
                const float mp = MLs[((p * 2 + qt2) * 16 + n16) * 2 + 0];
                const float lp = MLs[((p * 2 + qt2) * 16 + n16) * 2 + 1];
                const f16* ob = Obuf + (((p - 1) * 2 + qt2) * 64 + lane) * 16;
                half8 q0 = *(const half8*)(ob);
                half8 q1 = *(const half8*)(ob + 8);
                const float mn = fmaxf(m, mp);
                const float a1 = __builtin_exp2f(m - mn);
                const float a2 = __builtin_exp2f(mp - mn);
#pragma unroll
                for (int i = 0; i < 8; ++i) {
                    o[i]     = o[i] * a1 + (float)q0[i] * a2;
                    o[8 + i] = o[8 + i] * a1 + (float)q1[i] * a2;
                }
                l = l * a1 + lp * a2;
                m = mn;
            }
            const float scale = g / l;
            const int q = qt * 32 + qt2 * 16 + n16;
#pragma unroll
            for (int ct = 0; ct < 4; ++ct) {
                const size_t idx = (bN + q) * CC + ct * 16 + quad * 4;
                float4 xr = *(const float4*)(x + idx);
                float4 res;
                res.x = o[ct * 4 + 0] * scale + xr.x;
                res.y = o[ct * 4 + 1] * scale + xr.y;
                res.z = o[ct * 4 + 2] * scale + xr.z;
                res.w = o[ct * 4 + 3] * scale + xr.w;
                *(float4*)(out + idx) = res;
            }
        }
    }
}

extern "C" void kernel_launch(void* const* d_in, const int* in_sizes, int n_in,
                              void* d_out, int out_size, void* d_ws, size_t ws_size,
                              hipStream_t stream) {
    const float* x     = (const float*)d_in[0];
    const float* wq    = (const float*)d_in[1];
    const float* bq    = (const float*)d_in[2];
    const float* wk    = (const float*)d_in[3];
    const float* bk    = (const float*)d_in[4];
    const float* wv    = (const float*)d_in[5];
    const float* bv    = (const float*)d_in[6];
    const float* gamma = (const float*)d_in[7];
    float* out = (float*)d_out;

    f16* Qh = (f16*)d_ws;
    f16* Kf = Qh + (size_t)BB * NN * 8;
    f16* Vf = Kf + (size_t)BB * 256 * 128;

    proj_all_kernel<<<512, 256, 0, stream>>>(x, wq, bq, wk, bk, wv, bv, Qh, Kf, Vf);
    attn_kernel<<<BB * 128, 512, 0, stream>>>(Qh, Kf, Vf, x, gamma, out);
}

// Round 9
// 397.798 us; speedup vs baseline: 1.3092x; 1.3092x over previous
//
#include <hip/hip_runtime.h>
#include <hip/hip_bf16.h>

// ConvSelfAttn: B=8, N=4096, C=64, d=8. FP32 I/O.
// R9: occupancy via grid. attn: 256-thr blocks, 16 q/wave, key-split 4,
// grid 2048 (8 blocks/CU x 4 waves = 32 waves/CU). launch_bounds(256,8):
// both launch-bounds interpretations give a 64-VGPR cap (= R6 body's natural
// allocation). LDS 15.9KB/block (8 fit). Proj unchanged from R8.

#define BB 8
#define NN 4096
#define CC 64
#define PSTRIDE 72
#define LOG2E 1.44269504088896f

typedef _Float16 f16;
typedef _Float16 half8 __attribute__((ext_vector_type(8)));
typedef _Float16 half4 __attribute__((ext_vector_type(4)));
typedef __fp16 fp16x2 __attribute__((ext_vector_type(2)));
typedef float floatx4 __attribute__((ext_vector_type(4)));

static __device__ inline half4 pack4(float a, float b, float c, float d) {
    fp16x2 lo = __builtin_amdgcn_cvt_pkrtz(a, b);
    fp16x2 hi = __builtin_amdgcn_cvt_pkrtz(c, d);
    unsigned int lou = __builtin_bit_cast(unsigned int, lo);
    unsigned int hiu = __builtin_bit_cast(unsigned int, hi);
    unsigned long long packed = (unsigned long long)lou | ((unsigned long long)hiu << 32);
    return __builtin_bit_cast(half4, packed);
}

// ws layouts (halfs):
//   Qh    [B*N][8]                        row-major, Q pre-scaled by log2e
//   Kfrag [B][256 kblk][32 lane][4]       A-frag for 16x16x16 (quads 0-1)
//   Vfrag [B][128 kb32][4 ct][64 lane][8] A-frag for 16x16x32 PV

// ---------------- fused projection + fragment repack ----------------
__global__ __launch_bounds__(256) void proj_all_kernel(
    const float* __restrict__ x,
    const float* __restrict__ wq, const float* __restrict__ bq,
    const float* __restrict__ wk, const float* __restrict__ bk,
    const float* __restrict__ wv, const float* __restrict__ bv,
    f16* __restrict__ Qh, f16* __restrict__ Kf, f16* __restrict__ Vf)
{
    __shared__ alignas(16) f16 Ws[80][PSTRIDE];  // rows 0-63=V, 64-71=Q, 72-79=K
    __shared__ float Bs[80];
    __shared__ alignas(16) f16 Vs[64][68];       // [pixel][ch], pitch 68
    __shared__ alignas(16) f16 Ks[64][12];       // [pixel][ch]
    const int tid = threadIdx.x;

    for (int i = tid; i < 4096; i += 256) {
        int cin = i >> 6, cout = i & 63;
        Ws[cout][cin] = (f16)wv[i];
    }
    for (int i = tid; i < 512; i += 256) {
        int cin = i >> 3, c = i & 7;
        Ws[64 + c][cin] = (f16)(wq[i] * LOG2E);
        Ws[72 + c][cin] = (f16)wk[i];
    }
    if (tid < 80)
        Bs[tid] = (tid < 64) ? bv[tid]
                : (tid < 72 ? bq[tid - 64] * LOG2E : bk[tid - 72]);
    __syncthreads();

    const int wave = tid >> 6, lane = tid & 63;
    const int quad = lane >> 4, n16 = lane & 15;
    const long pb = (long)blockIdx.x * 64;
    const long p0 = pb + wave * 16;
    const int  b   = (int)(pb >> 12);
    const int  nnb = (int)(pb & 4095);

    half8 ax[2];
#pragma unroll
    for (int kh = 0; kh < 2; ++kh) {
        const float* xp = x + (p0 + n16) * 64 + kh * 32 + quad * 8;
        float4 x1 = *(const float4*)xp;
        float4 x2 = *(const float4*)(xp + 4);
        ax[kh][0] = (f16)x1.x; ax[kh][1] = (f16)x1.y;
        ax[kh][2] = (f16)x1.z; ax[kh][3] = (f16)x1.w;
        ax[kh][4] = (f16)x2.x; ax[kh][5] = (f16)x2.y;
        ax[kh][6] = (f16)x2.z; ax[kh][7] = (f16)x2.w;
    }

#pragma unroll
    for (int ct = 0; ct < 5; ++ct) {
        const int cout = (ct < 4) ? ct * 16 + n16 : 64 + n16;
        const float bias = Bs[cout];
        half8 b0 = *(const half8*)(&Ws[cout][quad * 8]);
        half8 b1 = *(const half8*)(&Ws[cout][32 + quad * 8]);
        floatx4 acc = {bias, bias, bias, bias};
        acc = __builtin_amdgcn_mfma_f32_16x16x32_f16(ax[0], b0, acc, 0, 0, 0);
        acc = __builtin_amdgcn_mfma_f32_16x16x32_f16(ax[1], b1, acc, 0, 0, 0);
        if (ct < 4) {
#pragma unroll
            for (int r = 0; r < 4; ++r)
                Vs[wave * 16 + quad * 4 + r][ct * 16 + n16] = (f16)acc[r];
        } else if (n16 < 8) {
            f16* dst = Qh + (p0 + quad * 4) * 8 + n16;
#pragma unroll
            for (int r = 0; r < 4; ++r) dst[r * 8] = (f16)acc[r];
        } else {
#pragma unroll
            for (int r = 0; r < 4; ++r)
                Ks[wave * 16 + quad * 4 + r][n16 - 8] = (f16)acc[r];
        }
    }
    __syncthreads();

#pragma unroll
    for (int u = 0; u < 2; ++u) {
        const int tt = wave * 2 + u;
        const int kb = tt >> 2, ct = tt & 3;
        half8 v;
#pragma unroll
        for (int j = 0; j < 8; ++j)
            v[j] = Vs[kb * 32 + quad * 8 + j][ct * 16 + n16];
        const size_t kbg = (size_t)b * 128 + (nnb >> 5) + kb;
        *(half8*)(Vf + (kbg * 4 + ct) * 512 + lane * 8) = v;
    }
    if (quad < 2) {
        half4 kv;
#pragma unroll
        for (int j = 0; j < 4; ++j)
            kv[j] = Ks[wave * 16 + n16][quad * 4 + j];
        const size_t kbg = (size_t)b * 256 + (nnb >> 4) + wave;
        *(half4*)(Kf + kbg * 128 + lane * 4) = kv;
    }
}

// ---------------- flash attention, S^T form, 16 q/wave, key-split 4 ----------------
// grid B*256 = 2048 x 256 thr; wave = ks (0..3): keys [ks*1024,+1024), 16 iters.
__global__ __launch_bounds__(256, 8) void attn_kernel(
    const f16* __restrict__ Qh, const f16* __restrict__ Kf,
    const f16* __restrict__ Vf,
    const float* __restrict__ x, const float* __restrict__ gptr,
    float* __restrict__ out)
{
    __shared__ alignas(16) f16 Pbuf[4 * 16 * PSTRIDE];   // 9.2 KB
    __shared__ alignas(16) f16 Obuf[3][64][16];          // 6 KB
    __shared__ float MLs[4][16][2];                      // 0.5 KB

    const int tid  = threadIdx.x;
    const int wave = tid >> 6, lane = tid & 63;
    const int quad = lane >> 4, n16 = lane & 15;
    const int ks = wave;                                 // 0..3

    const int b  = blockIdx.x & 7;                       // batch pinned to XCD
    const int qt = blockIdx.x >> 3;                      // 0..255 (16-query tile)
    const int q  = qt * 16 + n16;
    const size_t bN = (size_t)b * NN;

    // Q B-frag (16x16x16): quads 0-1 real, zeros persist elsewhere
    half4 bq4 = {0, 0, 0, 0};
    if (quad < 2) bq4 = *(const half4*)(Qh + (bN + q) * 8 + quad * 4);

    half4 ak[4];
#pragma unroll
    for (int t = 0; t < 4; ++t)
#pragma unroll
        for (int j = 0; j < 4; ++j) ak[t][j] = (f16)0.f;

    floatx4 oacc[4];
#pragma unroll
    for (int ct = 0; ct < 4; ++ct) oacc[ct] = (floatx4){0.f, 0.f, 0.f, 0.f};
    float m_run = -1e30f, l_loc = 0.f;

    const f16* kfb = Kf + ((size_t)b * 256 + ks * 64) * 128;
    const f16* vfb = Vf + ((size_t)b * 128 + ks * 32) * 2048;
    const floatx4 zero4 = {0.f, 0.f, 0.f, 0.f};
    f16* Pw = Pbuf + wave * 16 * PSTRIDE;

    for (int it = 0; it < 16; ++it) {
        // K frags: contiguous 256B per 16-key tile (quads 0-1)
        if (quad < 2) {
#pragma unroll
            for (int t = 0; t < 4; ++t)
                ak[t] = *(const half4*)(kfb + (it * 4 + t) * 128 + lane * 4);
        }
        // V first half: contiguous 1KB per ct
        half8 av0[4];
#pragma unroll
        for (int ct = 0; ct < 4; ++ct)
            av0[ct] = *(const half8*)(vfb + ((size_t)(it * 2) * 4 + ct) * 512 + lane * 8);

        // S^T = K Q^T: D[m=key=quad*4+r(+16t)][n=query=n16]
        floatx4 sf[4];
#pragma unroll
        for (int t = 0; t < 4; ++t)
            sf[t] = __builtin_amdgcn_mfma_f32_16x16x16f16(ak[t], bq4, zero4, 0, 0, 0);

        // V second half: issue under softmax
        half8 av1[4];
#pragma unroll
        for (int ct = 0; ct < 4; ++ct)
            av1[ct] = *(const half8*)(vfb + ((size_t)(it * 2 + 1) * 4 + ct) * 512 + lane * 8);

        // online softmax (exp2 domain; Q pre-scaled by log2e)
        float mx = sf[0][0];
#pragma unroll
        for (int t = 0; t < 4; ++t)
#pragma unroll
            for (int r = 0; r < 4; ++r) mx = fmaxf(mx, sf[t][r]);
        mx = fmaxf(mx, __shfl_xor(mx, 16, 64));
        mx = fmaxf(mx, __shfl_xor(mx, 32, 64));
        const float mnew = fmaxf(m_run, mx);
        const float alpha = __builtin_exp2f(m_run - mnew);
        m_run = mnew;
        float rs = 0.f;
#pragma unroll
        for (int t = 0; t < 4; ++t)
#pragma unroll
            for (int r = 0; r < 4; ++r) {
                float pv = __builtin_exp2f(sf[t][r] - mnew);
                sf[t][r] = pv;
                rs += pv;
            }
        l_loc = l_loc * alpha + rs;
#pragma unroll
        for (int ct = 0; ct < 4; ++ct) oacc[ct] *= alpha;

        // P^T -> per-wave LDS (b64 packed), read back as x32 B-frags
#pragma unroll
        for (int t = 0; t < 4; ++t) {
            half4 pk = pack4(sf[t][0], sf[t][1], sf[t][2], sf[t][3]);
            *(half4*)(Pw + n16 * PSTRIDE + t * 16 + quad * 4) = pk;
        }
        __asm__ volatile("s_waitcnt lgkmcnt(0)" ::: "memory");
        half8 bp0 = *(const half8*)(Pw + n16 * PSTRIDE + quad * 8);
        half8 bp1 = *(const half8*)(Pw + n16 * PSTRIDE + 32 + quad * 8);

        // O^T += V^T P^T
#pragma unroll
        for (int ct = 0; ct < 4; ++ct)
            oacc[ct] = __builtin_amdgcn_mfma_f32_16x16x32_f16(av0[ct], bp0, oacc[ct], 0, 0, 0);
#pragma unroll
        for (int ct = 0; ct < 4; ++ct)
            oacc[ct] = __builtin_amdgcn_mfma_f32_16x16x32_f16(av1[ct], bp1, oacc[ct], 0, 0, 0);
    }

    // fold per-lane l partials (lanes ^16,^32 share the query)
    float l_run = l_loc;
    l_run += __shfl_xor(l_run, 16, 64);
    l_run += __shfl_xor(l_run, 32, 64);

    __syncthreads();
    if (ks > 0) {
        if (quad == 0) {
            MLs[ks][n16][0] = m_run;
            MLs[ks][n16][1] = l_run;
        }
        half8 p0, p1;
#pragma unroll
        for (int i = 0; i < 4; ++i) {
            p0[i]     = (f16)oacc[0][i];
            p0[4 + i] = (f16)oacc[1][i];
            p1[i]     = (f16)oacc[2][i];
            p1[4 + i] = (f16)oacc[3][i];
        }
        *(half8*)(&Obuf[ks - 1][lane][0]) = p0;
        *(half8*)(&Obuf[ks - 1][lane][8]) = p1;
    }
    __syncthreads();
    if (ks == 0) {
        float m = m_run, l = l_run;
        float o[16];
#pragma unroll
        for (int ct = 0; ct < 4; ++ct)
#pragma unroll
            for (int r = 0; r < 4; ++r) o[ct * 4 + r] = oacc[ct][r];
#pragma unroll
        for (int p = 1; p < 4; ++p) {
            const float mp = MLs[p][n16][0];
            const float lp = MLs[p][n16][1];
            half8 q0 = *(const half8*)(&Obuf[p - 1][lane][0]);
            half8 q1 = *(const half8*)(&Obuf[p - 1][lane][8]);
            const float mn = fmaxf(m, mp);
            const float a1 = __builtin_exp2f(m - mn);
            const float a2 = __builtin_exp2f(mp - mn);
#pragma unroll
            for (int i = 0; i < 8; ++i) {
                o[i]     = o[i] * a1 + (float)q0[i] * a2;
                o[8 + i] = o[8 + i] * a1 + (float)q1[i] * a2;
            }
            l = l * a1 + lp * a2;
            m = mn;
        }
        const float scale = gptr[0] / l;
#pragma unroll
        for (int ct = 0; ct < 4; ++ct) {
            const size_t idx = (bN + q) * CC + ct * 16 + quad * 4;
            float4 xr = *(const float4*)(x + idx);
            float4 res;
            res.x = o[ct * 4 + 0] * scale + xr.x;
            res.y = o[ct * 4 + 1] * scale + xr.y;
            res.z = o[ct * 4 + 2] * scale + xr.z;
            res.w = o[ct * 4 + 3] * scale + xr.w;
            *(float4*)(out + idx) = res;
        }
    }
}

extern "C" void kernel_launch(void* const* d_in, const int* in_sizes, int n_in,
                              void* d_out, int out_size, void* d_ws, size_t ws_size,
                              hipStream_t stream) {
    const float* x     = (const float*)d_in[0];
    const float* wq    = (const float*)d_in[1];
    const float* bq    = (const float*)d_in[2];
    const float* wk    = (const float*)d_in[3];
    const float* bk    = (const float*)d_in[4];
    const float* wv    = (const float*)d_in[5];
    const float* bv    = (const float*)d_in[6];
    const float* gamma = (const float*)d_in[7];
    float* out = (float*)d_out;

    f16* Qh = (f16*)d_ws;
    f16* Kf = Qh + (size_t)BB * NN * 8;
    f16* Vf = Kf + (size_t)BB * 256 * 128;

    proj_all_kernel<<<512, 256, 0, stream>>>(x, wq, bq, wk, bk, wv, bv, Qh, Kf, Vf);
    attn_kernel<<<BB * 256, 256, 0, stream>>>(Qh, Kf, Vf, x, gamma, out);
}

// Round 10
// 130.403 us; speedup vs baseline: 3.9936x; 3.0505x over previous
//
#include <hip/hip_runtime.h>
#include <hip/hip_bf16.h>

// ConvSelfAttn: B=8, N=4096, C=64, d=8. FP32 I/O.
// R10: static-max softmax. m_fix = sqrt(qn2*Mk2) - 12 (Cauchy-Schwarz upper
// bound, exp2 domain) -> no online max, no alpha rescale, no cross-lane ops
// in the K-loop; key-split merge is a plain sum. Unconditional K loads
// (B-frag zeros cover k>=8). R6 shape: grid 1024 x 256, (256,4), 32 q/wave.

#define BB 8
#define NN 4096
#define CC 64
#define PSTRIDE 72
#define LOG2E 1.44269504088896f

typedef _Float16 f16;
typedef _Float16 half8 __attribute__((ext_vector_type(8)));
typedef _Float16 half4 __attribute__((ext_vector_type(4)));
typedef __fp16 fp16x2 __attribute__((ext_vector_type(2)));
typedef float floatx4 __attribute__((ext_vector_type(4)));

static __device__ inline half4 pack4(float a, float b, float c, float d) {
    fp16x2 lo = __builtin_amdgcn_cvt_pkrtz(a, b);
    fp16x2 hi = __builtin_amdgcn_cvt_pkrtz(c, d);
    unsigned int lou = __builtin_bit_cast(unsigned int, lo);
    unsigned int hiu = __builtin_bit_cast(unsigned int, hi);
    unsigned long long packed = (unsigned long long)lou | ((unsigned long long)hiu << 32);
    return __builtin_bit_cast(half4, packed);
}

// ws layout (see kernel_launch): Qh, Kf, Vf fragment-major as in R6, plus
// qn2 [B*N] f32 (||q'||^2), kn2 [B*N] f32 (||k||^2), Mk2 [B] f32.

// ---------------- fused projection + fragment repack + norms ----------------
__global__ __launch_bounds__(256) void proj_all_kernel(
    const float* __restrict__ x,
    const float* __restrict__ wq, const float* __restrict__ bq,
    const float* __restrict__ wk, const float* __restrict__ bk,
    const float* __restrict__ wv, const float* __restrict__ bv,
    f16* __restrict__ Qh, f16* __restrict__ Kf, f16* __restrict__ Vf,
    float* __restrict__ qn2, float* __restrict__ kn2)
{
    __shared__ alignas(16) f16 Ws[80][PSTRIDE];  // rows 0-63=V, 64-71=Q, 72-79=K
    __shared__ float Bs[80];
    __shared__ alignas(16) f16 Vs[64][68];       // [pixel][ch], pitch 68
    __shared__ alignas(16) f16 Ks[64][12];       // [pixel][ch]
    const int tid = threadIdx.x;

    for (int i = tid; i < 4096; i += 256) {
        int cin = i >> 6, cout = i & 63;
        Ws[cout][cin] = (f16)wv[i];
    }
    for (int i = tid; i < 512; i += 256) {
        int cin = i >> 3, c = i & 7;
        Ws[64 + c][cin] = (f16)(wq[i] * LOG2E);
        Ws[72 + c][cin] = (f16)wk[i];
    }
    if (tid < 80)
        Bs[tid] = (tid < 64) ? bv[tid]
                : (tid < 72 ? bq[tid - 64] * LOG2E : bk[tid - 72]);
    __syncthreads();

    const int wave = tid >> 6, lane = tid & 63;
    const int quad = lane >> 4, n16 = lane & 15;
    const long pb = (long)blockIdx.x * 64;
    const long p0 = pb + wave * 16;
    const int  b   = (int)(pb >> 12);
    const int  nnb = (int)(pb & 4095);

    half8 ax[2];
#pragma unroll
    for (int kh = 0; kh < 2; ++kh) {
        const float* xp = x + (p0 + n16) * 64 + kh * 32 + quad * 8;
        float4 x1 = *(const float4*)xp;
        float4 x2 = *(const float4*)(xp + 4);
        ax[kh][0] = (f16)x1.x; ax[kh][1] = (f16)x1.y;
        ax[kh][2] = (f16)x1.z; ax[kh][3] = (f16)x1.w;
        ax[kh][4] = (f16)x2.x; ax[kh][5] = (f16)x2.y;
        ax[kh][6] = (f16)x2.z; ax[kh][7] = (f16)x2.w;
    }

#pragma unroll
    for (int ct = 0; ct < 5; ++ct) {
        const int cout = (ct < 4) ? ct * 16 + n16 : 64 + n16;
        const float bias = Bs[cout];
        half8 b0 = *(const half8*)(&Ws[cout][quad * 8]);
        half8 b1 = *(const half8*)(&Ws[cout][32 + quad * 8]);
        floatx4 acc = {bias, bias, bias, bias};
        acc = __builtin_amdgcn_mfma_f32_16x16x32_f16(ax[0], b0, acc, 0, 0, 0);
        acc = __builtin_amdgcn_mfma_f32_16x16x32_f16(ax[1], b1, acc, 0, 0, 0);
        if (ct < 4) {
#pragma unroll
            for (int r = 0; r < 4; ++r)
                Vs[wave * 16 + quad * 4 + r][ct * 16 + n16] = (f16)acc[r];
        } else {
            // norms: sum acc^2 across the 8 cout lanes (bits 0..2 of lane)
            float n2[4];
#pragma unroll
            for (int r = 0; r < 4; ++r) n2[r] = acc[r] * acc[r];
#pragma unroll
            for (int d = 1; d < 8; d <<= 1)
#pragma unroll
                for (int r = 0; r < 4; ++r) n2[r] += __shfl_xor(n2[r], d, 64);
            if (n16 == 0) {
#pragma unroll
                for (int r = 0; r < 4; ++r) qn2[p0 + quad * 4 + r] = n2[r];
            } else if (n16 == 8) {
#pragma unroll
                for (int r = 0; r < 4; ++r) kn2[p0 + quad * 4 + r] = n2[r];
            }
            if (n16 < 8) {
                f16* dst = Qh + (p0 + quad * 4) * 8 + n16;
#pragma unroll
                for (int r = 0; r < 4; ++r) dst[r * 8] = (f16)acc[r];
            } else {
#pragma unroll
                for (int r = 0; r < 4; ++r)
                    Ks[wave * 16 + quad * 4 + r][n16 - 8] = (f16)acc[r];
            }
        }
    }
    __syncthreads();

#pragma unroll
    for (int u = 0; u < 2; ++u) {
        const int tt = wave * 2 + u;
        const int kb = tt >> 2, ct = tt & 3;
        half8 v;
#pragma unroll
        for (int j = 0; j < 8; ++j)
            v[j] = Vs[kb * 32 + quad * 8 + j][ct * 16 + n16];
        const size_t kbg = (size_t)b * 128 + (nnb >> 5) + kb;
        *(half8*)(Vf + (kbg * 4 + ct) * 512 + lane * 8) = v;
    }
    if (quad < 2) {
        half4 kv;
#pragma unroll
        for (int j = 0; j < 4; ++j)
            kv[j] = Ks[wave * 16 + n16][quad * 4 + j];
        const size_t kbg = (size_t)b * 256 + (nnb >> 4) + wave;
        *(half4*)(Kf + kbg * 128 + lane * 4) = kv;
    }
}

// ---------------- per-batch max key-norm reduce ----------------
__global__ __launch_bounds__(256) void knorm_max_kernel(
    const float* __restrict__ kn2, float* __restrict__ Mk2)
{
    __shared__ float red[4];
    const int b = blockIdx.x, tid = threadIdx.x;
    float mx = 0.f;
    for (int i = tid; i < NN; i += 256) mx = fmaxf(mx, kn2[(size_t)b * NN + i]);
#pragma unroll
    for (int d = 1; d < 64; d <<= 1) mx = fmaxf(mx, __shfl_xor(mx, d, 64));
    if ((tid & 63) == 0) red[tid >> 6] = mx;
    __syncthreads();
    if (tid == 0) {
        float m = fmaxf(fmaxf(red[0], red[1]), fmaxf(red[2], red[3]));
        Mk2[b] = m;
    }
}

// ---------------- flash attention, static-max, 32 q/wave, key-split 4 ----------------
// grid B*128 = 1024 x 256 thr; wave = ks (0..3): keys [ks*1024,+1024), 16 iters.
__global__ __launch_bounds__(256, 4) void attn_kernel(
    const f16* __restrict__ Qh, const f16* __restrict__ Kf,
    const f16* __restrict__ Vf,
    const float* __restrict__ qn2, const float* __restrict__ Mk2,
    const float* __restrict__ x, const float* __restrict__ gptr,
    float* __restrict__ out)
{
    // union: Pbuf (4 waves x 2 subtiles x 16*72 halfs = 18.4KB) during K-loop;
    // Obuf (3 x 2 x 64 x 16 f32 = 24KB) after the barrier.
    __shared__ alignas(16) char smem[24576];
    f16*   Pbuf = (f16*)smem;
    float* Obuf = (float*)smem;
    __shared__ float Ls[4][2][16];

    const int tid  = threadIdx.x;
    const int wave = tid >> 6, lane = tid & 63;
    const int quad = lane >> 4, n16 = lane & 15;
    const int ks = wave;

    const int b  = blockIdx.x & 7;
    const int qt = blockIdx.x >> 3;               // 0..127 (32-query tile)
    const size_t bN = (size_t)b * NN;

    const float mk2 = Mk2[b];

    // Q B-frags (16x16x16): quads 0-1 real, zeros elsewhere (covers garbage K)
    half4 bq4[2];
    float mfix[2];
#pragma unroll
    for (int qt2 = 0; qt2 < 2; ++qt2) {
        const int q = qt * 32 + qt2 * 16 + n16;
#pragma unroll
        for (int j = 0; j < 4; ++j) bq4[qt2][j] = (f16)0.f;
        if (quad < 2)
            bq4[qt2] = *(const half4*)(Qh + (bN + q) * 8 + quad * 4);
        mfix[qt2] = __builtin_sqrtf(qn2[bN + q] * mk2) - 12.0f;
    }

    floatx4 oacc[2][4];
#pragma unroll
    for (int qt2 = 0; qt2 < 2; ++qt2)
#pragma unroll
        for (int ct = 0; ct < 4; ++ct) oacc[qt2][ct] = (floatx4){0.f, 0.f, 0.f, 0.f};
    float l_loc[2] = {0.f, 0.f};

    const f16* kfb = Kf + ((size_t)b * 256 + ks * 64) * 128;
    const f16* vfb = Vf + ((size_t)b * 128 + ks * 32) * 2048;
    const floatx4 zero4 = {0.f, 0.f, 0.f, 0.f};
    f16* Pw0 = Pbuf + (wave * 2 + 0) * 16 * PSTRIDE;
    f16* Pw1 = Pbuf + (wave * 2 + 1) * 16 * PSTRIDE;

    for (int it = 0; it < 16; ++it) {
        // K frags: unconditional (quads 2-3 garbage is zeroed by B-frag)
        half4 ak[4];
#pragma unroll
        for (int t = 0; t < 4; ++t)
            ak[t] = *(const half4*)(kfb + (it * 4 + t) * 128 + lane * 4);
        half8 av0[4];
#pragma unroll
        for (int ct = 0; ct < 4; ++ct)
            av0[ct] = *(const half8*)(vfb + ((size_t)(it * 2) * 4 + ct) * 512 + lane * 8);

        floatx4 sf[4];
#pragma unroll
        for (int t = 0; t < 4; ++t)
            sf[t] = __builtin_amdgcn_mfma_f32_16x16x16f16(ak[t], bq4[0], zero4, 0, 0, 0);

        half8 av1[4];
#pragma unroll
        for (int ct = 0; ct < 4; ++ct)
            av1[ct] = *(const half8*)(vfb + ((size_t)(it * 2 + 1) * 4 + ct) * 512 + lane * 8);

#pragma unroll
        for (int qt2 = 0; qt2 < 2; ++qt2) {
            if (qt2 == 1) {
#pragma unroll
                for (int t = 0; t < 4; ++t)
                    sf[t] = __builtin_amdgcn_mfma_f32_16x16x16f16(ak[t], bq4[1], zero4, 0, 0, 0);
            }
            const float mf = mfix[qt2];
            float rs = 0.f;
#pragma unroll
            for (int t = 0; t < 4; ++t)
#pragma unroll
                for (int r = 0; r < 4; ++r) {
                    float pv = __builtin_exp2f(sf[t][r] - mf);
                    sf[t][r] = pv;
                    rs += pv;
                }
            l_loc[qt2] += rs;
            f16* Pw = qt2 ? Pw1 : Pw0;
#pragma unroll
            for (int t = 0; t < 4; ++t) {
                half4 pk = pack4(sf[t][0], sf[t][1], sf[t][2], sf[t][3]);
                *(half4*)(Pw + n16 * PSTRIDE + t * 16 + quad * 4) = pk;
            }
        }
        __asm__ volatile("s_waitcnt lgkmcnt(0)" ::: "memory");

#pragma unroll
        for (int qt2 = 0; qt2 < 2; ++qt2) {
            f16* Pw = qt2 ? Pw1 : Pw0;
            half8 bp0 = *(const half8*)(Pw + n16 * PSTRIDE + quad * 8);
            half8 bp1 = *(const half8*)(Pw + n16 * PSTRIDE + 32 + quad * 8);
#pragma unroll
            for (int ct = 0; ct < 4; ++ct)
                oacc[qt2][ct] = __builtin_amdgcn_mfma_f32_16x16x32_f16(av0[ct], bp0, oacc[qt2][ct], 0, 0, 0);
#pragma unroll
            for (int ct = 0; ct < 4; ++ct)
                oacc[qt2][ct] = __builtin_amdgcn_mfma_f32_16x16x32_f16(av1[ct], bp1, oacc[qt2][ct], 0, 0, 0);
        }
    }

    // fold per-lane l partials (lanes ^16,^32 share the query)
    float l_run[2];
#pragma unroll
    for (int qt2 = 0; qt2 < 2; ++qt2) {
        float l = l_loc[qt2];
        l += __shfl_xor(l, 16, 64);
        l += __shfl_xor(l, 32, 64);
        l_run[qt2] = l;
    }

    __syncthreads();   // all P reads done; reuse Pbuf memory as Obuf (f32)
    if (ks > 0) {
#pragma unroll
        for (int qt2 = 0; qt2 < 2; ++qt2) {
            if (quad == 0) Ls[ks][qt2][n16] = l_run[qt2];
            float* ob = Obuf + (((ks - 1) * 2 + qt2) * 64 + lane) * 16;
#pragma unroll
            for (int ct = 0; ct < 4; ++ct)
                *(floatx4*)(ob + ct * 4) = oacc[qt2][ct];
        }
    }
    __syncthreads();
    if (ks == 0) {
        const float g = gptr[0];
#pragma unroll
        for (int qt2 = 0; qt2 < 2; ++qt2) {
            float l = l_run[qt2];
            float o[16];
#pragma unroll
            for (int ct = 0; ct < 4; ++ct)
#pragma unroll
                for (int r = 0; r < 4; ++r) o[ct * 4 + r] = oacc[qt2][ct][r];
#pragma unroll
            for (int p = 1; p < 4; ++p) {
                l += Ls[p][qt2][n16];
                const float* ob = Obuf + (((p - 1) * 2 + qt2) * 64 + lane) * 16;
#pragma unroll
                for (int i = 0; i < 16; ++i) o[i] += ob[i];
            }
            const float scale = g / l;
            const int q = qt * 32 + qt2 * 16 + n16;
#pragma unroll
            for (int ct = 0; ct < 4; ++ct) {
                const size_t idx = (bN + q) * CC + ct * 16 + quad * 4;
                float4 xr = *(const float4*)(x + idx);
                float4 res;
                res.x = o[ct * 4 + 0] * scale + xr.x;
                res.y = o[ct * 4 + 1] * scale + xr.y;
                res.z = o[ct * 4 + 2] * scale + xr.z;
                res.w = o[ct * 4 + 3] * scale + xr.w;
                *(float4*)(out + idx) = res;
            }
        }
    }
}

extern "C" void kernel_launch(void* const* d_in, const int* in_sizes, int n_in,
                              void* d_out, int out_size, void* d_ws, size_t ws_size,
                              hipStream_t stream) {
    const float* x     = (const float*)d_in[0];
    const float* wq    = (const float*)d_in[1];
    const float* bq    = (const float*)d_in[2];
    const float* wk    = (const float*)d_in[3];
    const float* bk    = (const float*)d_in[4];
    const float* wv    = (const float*)d_in[5];
    const float* bv    = (const float*)d_in[6];
    const float* gamma = (const float*)d_in[7];
    float* out = (float*)d_out;

    // ws: Qh 512KB | Kf 512KB | Vf 4MB | qn2 128KB | kn2 128KB | Mk2 32B
    f16* Qh = (f16*)d_ws;
    f16* Kf = Qh + (size_t)BB * NN * 8;
    f16* Vf = Kf + (size_t)BB * 256 * 128;
    float* qn2 = (float*)(Vf + (size_t)BB * 128 * 4 * 512);
    float* kn2 = qn2 + (size_t)BB * NN;
    float* Mk2 = kn2 + (size_t)BB * NN;

    proj_all_kernel<<<512, 256, 0, stream>>>(x, wq, bq, wk, bk, wv, bv,
                                             Qh, Kf, Vf, qn2, kn2);
    knorm_max_kernel<<<BB, 256, 0, stream>>>(kn2, Mk2);
    attn_kernel<<<BB * 128, 256, 0, stream>>>(Qh, Kf, Vf, qn2, Mk2, x, gamma, out);
}